// Round 5
// baseline (326.763 us; speedup 1.0000x reference)
//
#include <hip/hip_runtime.h>
#include <math.h>

#define T_STEPS 32
#define B_SZ    512
#define D_SZ    1024
#define C_SZ    1000
#define KZ      8           // GEMM2 split-K factor
#define HP      132         // LDS h-tile pitch (bf16); breaks bank aliasing
#define NBLK    512         // fused grid: 2 blocks/CU @ 64 KiB LDS (cap = 1024)

typedef __bf16 bf16x8 __attribute__((ext_vector_type(8)));
typedef float  f32x4  __attribute__((ext_vector_type(4)));

__device__ __forceinline__ unsigned short f2bf(float f) {
    unsigned u = __float_as_uint(f);
    unsigned r = u + 0x7FFFu + ((u >> 16) & 1u);   // RNE
    return (unsigned short)(r >> 16);
}
__device__ __forceinline__ float bf2f(unsigned short b) {
    return __uint_as_float(((unsigned)b) << 16);
}

__device__ __forceinline__ void async_copy16(const void* g, void* l) {
    __builtin_amdgcn_global_load_lds(
        (const __attribute__((address_space(1))) unsigned int*)g,
        (__attribute__((address_space(3))) unsigned int*)l,
        16, 0, 0);
}

// ---------------- cast sizes --------------------------------------------------
#define NX4   4194304   // X:  16M floats / 4
#define NW14  262144    // W1:  1M floats / 4
#define NW24  256000    // W2: 1.024M floats / 4
#define NCTOT (NX4 + NW14 + NW24)    // 4,712,448 = 18,408 * 256

// ---------------- self-resetting grid barrier (capture-safe, no coop) ---------
// Arrive counter c + exit counter e. Reset (by LAST exiter) only fires after
// every block has left the spin -> provably no reset/spin race. State returns
// to 0 after each use => safe across graph replays; hipMemsetAsync covers the
// first (dirty-workspace) run. Spin guard: escape after ~1.7 s so a broken
// residency assumption fails the absmax check instead of hanging the container.
__device__ __forceinline__ void grid_sync(unsigned* c, unsigned* e) {
    __syncthreads();
    if (threadIdx.x == 0) {
        __threadfence();                               // release phase writes
        atomicAdd(c, 1u);
        int guard = 0;
        while (__hip_atomic_load(c, __ATOMIC_RELAXED, __HIP_MEMORY_SCOPE_AGENT)
               < (unsigned)NBLK) {
            __builtin_amdgcn_s_sleep(8);
            if (++guard > 4000000) break;              // fail loud, don't hang
        }
        __threadfence();                               // acquire others' writes
        if (atomicAdd(e, 1u) == (unsigned)NBLK - 1u) {
            __hip_atomic_store(c, 0u, __ATOMIC_RELAXED, __HIP_MEMORY_SCOPE_AGENT);
            __hip_atomic_store(e, 0u, __ATOMIC_RELAXED, __HIP_MEMORY_SCOPE_AGENT);
        }
    }
    __syncthreads();
}

// ================= standalone kernels (fallback chain, R3-proven) =============

__global__ __launch_bounds__(256) void cast_all_k(
    const float* __restrict__ X,  unsigned short* __restrict__ X_bf,
    const float* __restrict__ W1, unsigned short* __restrict__ W1_bf,
    const float* __restrict__ W2, unsigned short* __restrict__ W2_bf)
{
    const int idx = blockIdx.x * 256 + threadIdx.x;
    const float4* s; ushort4* d; int j;
    if (idx < NX4)              { s = (const float4*)X;  d = (ushort4*)X_bf;  j = idx; }
    else if (idx < NX4 + NW14)  { s = (const float4*)W1; d = (ushort4*)W1_bf; j = idx - NX4; }
    else                        { s = (const float4*)W2; d = (ushort4*)W2_bf; j = idx - NX4 - NW14; }
    const float4 v = s[j];
    ushort4 o;
    o.x = f2bf(v.x); o.y = f2bf(v.y); o.z = f2bf(v.z); o.w = f2bf(v.w);
    d[j] = o;
}

__global__ __launch_bounds__(256) void gemm1_scan_bf_k(
    const unsigned short* __restrict__ Xb, const unsigned short* __restrict__ Bm,
    const float* __restrict__ bias, unsigned short* __restrict__ cnt)
{
    __shared__ __align__(16) unsigned short smem[32768];   // 64 KiB

    const int tid  = threadIdx.x;
    const int wave = tid >> 6;
    const int lane = tid & 63;
    const int lm   = lane & 15;
    const int quad = lane >> 4;
    const int wm   = (wave >> 1) * 64;
    const int wn   = (wave & 1) * 64;

    const int f  = blockIdx.x;
    const int rr = f >> 9;
    const int cc = f & 7;
    const int ss = (f >> 3) & 63;
    const int xb = ss & 7;
    const int yb = rr * 64 + (ss >> 3) * 8 + cc;
    const int b0 = yb * 4;
    const int n0 = xb * 128;

    f32x4 acc[4][4];
    #pragma unroll
    for (int i = 0; i < 4; ++i)
        #pragma unroll
        for (int j = 0; j < 4; ++j)
            acc[i][j] = (f32x4){0.f, 0.f, 0.f, 0.f};

    int srow[4], sgq[4];
    size_t aoff[4];
    unsigned ldsoff[4];
    #pragma unroll
    for (int p = 0; p < 4; ++p) {
        const int s = p * 256 + tid;
        const int rho = s >> 3;
        srow[p] = rho;
        sgq[p]  = (s & 7) ^ (rho & 7);
        aoff[p] = (size_t)((rho >> 2) * 512 + b0 + (rho & 3)) * D_SZ;
        ldsoff[p] = (unsigned)(p * 256 + wave * 64) * 16u;
    }
    const int fq0 = quad ^ (lm & 7);

#define STAGE(buf_, k0_) do {                                                    \
        char* abase = (char*)smem + (buf_) * 16384;                              \
        char* bbase = (char*)smem + 32768 + (buf_) * 16384;                      \
        _Pragma("unroll")                                                        \
        for (int p = 0; p < 4; ++p)                                              \
            async_copy16(Xb + aoff[p] + (k0_) + sgq[p] * 8,                      \
                         abase + ldsoff[p]);                                     \
        _Pragma("unroll")                                                        \
        for (int p = 0; p < 4; ++p)                                              \
            async_copy16(Bm + (size_t)(n0 + srow[p]) * D_SZ + (k0_) + sgq[p] * 8,\
                         bbase + ldsoff[p]);                                     \
    } while (0)

#define COMPUTE(buf_) do {                                                       \
        const bf16x8* Ar = (const bf16x8*)((char*)smem + (buf_) * 16384);        \
        const bf16x8* Br = (const bf16x8*)((char*)smem + 32768 + (buf_) * 16384);\
        __builtin_amdgcn_s_setprio(1);                                           \
        _Pragma("unroll")                                                        \
        for (int kk = 0; kk < 2; ++kk) {                                         \
            const int fqk = fq0 ^ (kk * 4);                                      \
            bf16x8 af[4], bfr[4];                                                \
            _Pragma("unroll")                                                    \
            for (int i2 = 0; i2 < 4; ++i2) {                                     \
                af[i2]  = Ar[(wm + i2 * 16 + lm) * 8 + fqk];                     \
                bfr[i2] = Br[(wn + i2 * 16 + lm) * 8 + fqk];                     \
            }                                                                    \
            _Pragma("unroll")                                                    \
            for (int mi = 0; mi < 4; ++mi)                                       \
                _Pragma("unroll")                                                \
                for (int ni = 0; ni < 4; ++ni)                                   \
                    acc[mi][ni] = __builtin_amdgcn_mfma_f32_16x16x32_bf16(       \
                        af[mi], bfr[ni], acc[mi][ni], 0, 0, 0);                  \
        }                                                                        \
        __builtin_amdgcn_s_setprio(0);                                           \
    } while (0)

    STAGE(0, 0);
    __syncthreads();

    for (int t = 0; t < 14; t += 2) {
        STAGE(1, (t + 1) * 64);
        COMPUTE(0);
        __syncthreads();
        STAGE(0, (t + 2) * 64);
        COMPUTE(1);
        __syncthreads();
    }
    STAGE(1, 15 * 64);
    COMPUTE(0);
    __syncthreads();
    COMPUTE(1);
    __syncthreads();

#undef STAGE
#undef COMPUTE

    #pragma unroll
    for (int ni = 0; ni < 4; ++ni) {
        const int nn = wn + ni * 16 + lm;
        const float bv = bias[n0 + nn];
        #pragma unroll
        for (int mi = 0; mi < 4; ++mi) {
            const f32x4 v = acc[mi][ni];
            #pragma unroll
            for (int q = 0; q < 4; ++q)
                smem[(wm + mi * 16 + quad * 4 + q) * HP + nn] = f2bf(v[q] + bv);
        }
    }
    __syncthreads();

    {
        const unsigned* smemU = (const unsigned*)smem;
        const int bb = tid >> 6;
        const int c2 = tid & 63;
        float v0 = 0.f, cv0 = 0.f, v1 = 0.f, cv1 = 0.f;
        #pragma unroll
        for (int t = 0; t < T_STEPS; ++t) {
            const unsigned u = smemU[(t * 4 + bb) * (HP / 2) + c2];
            const float h0 = bf2f((unsigned short)(u & 0xFFFFu));
            const float h1 = bf2f((unsigned short)(u >> 16));
            v0 = 0.5f * (v0 + h0);
            const float s0 = (v0 >= 1.0f) ? 1.0f : 0.0f;
            cv0 += s0; v0 *= (1.0f - s0);
            v1 = 0.5f * (v1 + h1);
            const float s1 = (v1 >= 1.0f) ? 1.0f : 0.0f;
            cv1 += s1; v1 *= (1.0f - s1);
        }
        ushort2 o;
        o.x = f2bf(cv0); o.y = f2bf(cv1);
        *(ushort2*)&cnt[(size_t)(b0 + bb) * D_SZ + n0 + 2 * c2] = o;
    }
}

__global__ __launch_bounds__(256) void gemm2_splitk_k(
    const unsigned short* __restrict__ A, const unsigned short* __restrict__ Bm,
    float* __restrict__ partial)
{
    __shared__ __align__(16) unsigned short As[128 * 32];
    __shared__ __align__(16) unsigned short Bs[128 * 32];

    const int tid  = threadIdx.x;
    const int wave = tid >> 6;
    const int lane = tid & 63;
    const int lm   = lane & 15;
    const int quad = lane >> 4;
    const int wm   = (wave >> 1) * 64;
    const int wn   = (wave & 1) * 64;
    const int n0   = blockIdx.x * 128;
    const int m0   = blockIdx.y * 128;
    const int kz   = blockIdx.z;

    f32x4 acc[4][4];
    #pragma unroll
    for (int i = 0; i < 4; ++i)
        #pragma unroll
        for (int j = 0; j < 4; ++j)
            acc[i][j] = (f32x4){0.f, 0.f, 0.f, 0.f};

    int srow[2], sgq[2];
    unsigned ldsoff[2];
    #pragma unroll
    for (int p = 0; p < 2; ++p) {
        const int s = p * 256 + tid;
        srow[p] = s >> 2;
        sgq[p]  = (s & 3) ^ ((srow[p] >> 1) & 3);
        ldsoff[p] = (unsigned)(p * 256 + wave * 64) * 16u;
    }
    const int fq = quad ^ ((lm >> 1) & 3);

    const int kbeg = kz * (D_SZ / KZ);
    for (int k0 = kbeg; k0 < kbeg + D_SZ / KZ; k0 += 32) {
        #pragma unroll
        for (int p = 0; p < 2; ++p) {
            async_copy16(A + (size_t)(m0 + srow[p]) * D_SZ + k0 + sgq[p] * 8,
                         (char*)As + ldsoff[p]);
            int brow = n0 + srow[p];
            if (brow > C_SZ - 1) brow = C_SZ - 1;
            async_copy16(Bm + (size_t)brow * D_SZ + k0 + sgq[p] * 8,
                         (char*)Bs + ldsoff[p]);
        }
        __syncthreads();

        bf16x8 af[4], bfr[4];
        #pragma unroll
        for (int i = 0; i < 4; ++i) {
            af[i]  = ((const bf16x8*)As)[(wm + i * 16 + lm) * 4 + fq];
            bfr[i] = ((const bf16x8*)Bs)[(wn + i * 16 + lm) * 4 + fq];
        }
        #pragma unroll
        for (int mi = 0; mi < 4; ++mi)
            #pragma unroll
            for (int ni = 0; ni < 4; ++ni)
                acc[mi][ni] = __builtin_amdgcn_mfma_f32_16x16x32_bf16(
                    af[mi], bfr[ni], acc[mi][ni], 0, 0, 0);
        __syncthreads();
    }

    #pragma unroll
    for (int ni = 0; ni < 4; ++ni) {
        const int nn = n0 + wn + ni * 16 + lm;
        if (nn >= C_SZ) continue;
        #pragma unroll
        for (int mi = 0; mi < 4; ++mi) {
            const f32x4 v = acc[mi][ni];
            #pragma unroll
            for (int q = 0; q < 4; ++q) {
                const int mm = m0 + wm + mi * 16 + quad * 4 + q;
                partial[((size_t)kz * B_SZ + mm) * C_SZ + nn] = v[q];
            }
        }
    }
}

__global__ __launch_bounds__(256) void reduce_lsm_k(
    const float* __restrict__ partial, const float* __restrict__ b2,
    float* __restrict__ out)
{
    __shared__ float red_max[4];
    __shared__ float red_sum[4];

    const int b   = blockIdx.x;
    const int tid = threadIdx.x;

    float vals[4];
    float m = -1e30f;
    #pragma unroll
    for (int k = 0; k < 4; ++k) {
        const int c = tid + k * 256;
        if (c < C_SZ) {
            float s = 0.f;
            #pragma unroll
            for (int z = 0; z < KZ; ++z)
                s += partial[((size_t)z * B_SZ + b) * C_SZ + c];
            vals[k] = s * (1.0f / (float)T_STEPS) + b2[c];
        } else {
            vals[k] = -1e30f;
        }
        m = fmaxf(m, vals[k]);
    }
    #pragma unroll
    for (int off = 32; off > 0; off >>= 1)
        m = fmaxf(m, __shfl_down(m, off, 64));
    const int wave = tid >> 6;
    const int lane = tid & 63;
    if (lane == 0) red_max[wave] = m;
    __syncthreads();
    m = fmaxf(fmaxf(red_max[0], red_max[1]), fmaxf(red_max[2], red_max[3]));

    float s = 0.f;
    #pragma unroll
    for (int k = 0; k < 4; ++k) {
        const int c = tid + k * 256;
        if (c < C_SZ) s += __expf(vals[k] - m);
    }
    #pragma unroll
    for (int off = 32; off > 0; off >>= 1)
        s += __shfl_down(s, off, 64);
    if (lane == 0) red_sum[wave] = s;
    __syncthreads();
    s = red_sum[0] + red_sum[1] + red_sum[2] + red_sum[3];

    const float lse = m + logf(s);
    #pragma unroll
    for (int k = 0; k < 4; ++k) {
        const int c = tid + k * 256;
        if (c < C_SZ) out[(size_t)b * C_SZ + c] = vals[k] - lse;
    }
}

// ================= fused mega-kernel (plain launch + spin barriers) ===========
// 512 blocks x 256 threads, 64 KiB LDS, __launch_bounds__(256,2) -> exactly
// 2 blocks/CU, capacity 1024 >= 512 -> all blocks resident (barrier-safe).
// Phase 1: grid-stride cast. Phase 2: gemm1+LIF, 2 tiles/block (R3 swizzle on
// fidx = r*512+bid). Phase 3: gemm2 split-K on bid<256. Phase 4: reduce+lsm.
__global__ __launch_bounds__(256, 2) void fused_all_k(
    const float* __restrict__ X,  const float* __restrict__ W1,
    const float* __restrict__ b1, const float* __restrict__ W2,
    const float* __restrict__ b2,
    unsigned short* __restrict__ X_bf, unsigned short* __restrict__ W1_bf,
    unsigned short* __restrict__ W2_bf, unsigned short* __restrict__ cnt,
    float* __restrict__ partial, float* __restrict__ out,
    unsigned* __restrict__ bar)
{
    __shared__ __align__(16) unsigned short smem[32768];   // 64 KiB exactly

    const int tid = threadIdx.x;
    const int bid = blockIdx.x;

    // ---- phase 1: cast X, W1, W2 -> bf16 (grid-stride) ----
    for (int idx = bid * 256 + tid; idx < NCTOT; idx += NBLK * 256) {
        const float4* s; ushort4* d; int j;
        if (idx < NX4)             { s = (const float4*)X;  d = (ushort4*)X_bf;  j = idx; }
        else if (idx < NX4 + NW14) { s = (const float4*)W1; d = (ushort4*)W1_bf; j = idx - NX4; }
        else                       { s = (const float4*)W2; d = (ushort4*)W2_bf; j = idx - NX4 - NW14; }
        const float4 v = s[j];
        ushort4 o;
        o.x = f2bf(v.x); o.y = f2bf(v.y); o.z = f2bf(v.z); o.w = f2bf(v.w);
        d[j] = o;
    }
    grid_sync(bar + 0, bar + 1);

    // ---- phase 2: gemm1 + bias + LIF scan, 2 tiles per block ----
    {
        const int wave = tid >> 6;
        const int lane = tid & 63;
        const int lm   = lane & 15;
        const int quad = lane >> 4;
        const int wm   = (wave >> 1) * 64;
        const int wn   = (wave & 1) * 64;
        const int fq0  = quad ^ (lm & 7);
        const unsigned short* Xb = X_bf;
        const unsigned short* Wb = W1_bf;

#define STG(buf_, k0_) do {                                                      \
        char* abase = (char*)smem + (buf_) * 16384;                              \
        char* bbase = (char*)smem + 32768 + (buf_) * 16384;                      \
        _Pragma("unroll")                                                        \
        for (int p = 0; p < 4; ++p)                                              \
            async_copy16(Xb + aoff[p] + (k0_) + sgq[p] * 8,                      \
                         abase + ldsoff[p]);                                     \
        _Pragma("unroll")                                                        \
        for (int p = 0; p < 4; ++p)                                              \
            async_copy16(Wb + (size_t)(n0 + srow[p]) * D_SZ + (k0_) + sgq[p] * 8,\
                         bbase + ldsoff[p]);                                     \
    } while (0)

#define CMP(buf_) do {                                                           \
        const bf16x8* Ar = (const bf16x8*)((char*)smem + (buf_) * 16384);        \
        const bf16x8* Br = (const bf16x8*)((char*)smem + 32768 + (buf_) * 16384);\
        __builtin_amdgcn_s_setprio(1);                                           \
        _Pragma("unroll")                                                        \
        for (int kk = 0; kk < 2; ++kk) {                                         \
            const int fqk = fq0 ^ (kk * 4);                                      \
            bf16x8 af[4], bfr[4];                                                \
            _Pragma("unroll")                                                    \
            for (int i2 = 0; i2 < 4; ++i2) {                                     \
                af[i2]  = Ar[(wm + i2 * 16 + lm) * 8 + fqk];                     \
                bfr[i2] = Br[(wn + i2 * 16 + lm) * 8 + fqk];                     \
            }                                                                    \
            _Pragma("unroll")                                                    \
            for (int mi = 0; mi < 4; ++mi)                                       \
                _Pragma("unroll")                                                \
                for (int ni = 0; ni < 4; ++ni)                                   \
                    acc[mi][ni] = __builtin_amdgcn_mfma_f32_16x16x32_bf16(       \
                        af[mi], bfr[ni], acc[mi][ni], 0, 0, 0);                  \
        }                                                                        \
        __builtin_amdgcn_s_setprio(0);                                           \
    } while (0)

        for (int r = 0; r < 2; ++r) {
            const int fidx = r * NBLK + bid;
            const int rr = fidx >> 9;
            const int cc = fidx & 7;
            const int ss = (fidx >> 3) & 63;
            const int xb = ss & 7;
            const int yb = rr * 64 + (ss >> 3) * 8 + cc;
            const int b0 = yb * 4;
            const int n0 = xb * 128;

            f32x4 acc[4][4];
            #pragma unroll
            for (int i = 0; i < 4; ++i)
                #pragma unroll
                for (int j = 0; j < 4; ++j)
                    acc[i][j] = (f32x4){0.f, 0.f, 0.f, 0.f};

            int srow[4], sgq[4];
            size_t aoff[4];
            unsigned ldsoff[4];
            #pragma unroll
            for (int p = 0; p < 4; ++p) {
                const int s = p * 256 + tid;
                const int rho = s >> 3;
                srow[p] = rho;
                sgq[p]  = (s & 7) ^ (rho & 7);
                aoff[p] = (size_t)((rho >> 2) * 512 + b0 + (rho & 3)) * D_SZ;
                ldsoff[p] = (unsigned)(p * 256 + wave * 64) * 16u;
            }

            STG(0, 0);
            __syncthreads();
            for (int t = 0; t < 14; t += 2) {
                STG(1, (t + 1) * 64);
                CMP(0);
                __syncthreads();
                STG(0, (t + 2) * 64);
                CMP(1);
                __syncthreads();
            }
            STG(1, 15 * 64);
            CMP(0);
            __syncthreads();
            CMP(1);
            __syncthreads();

            // h-tile (+bias) -> LDS
            #pragma unroll
            for (int ni = 0; ni < 4; ++ni) {
                const int nn = wn + ni * 16 + lm;
                const float bv = b1[n0 + nn];
                #pragma unroll
                for (int mi = 0; mi < 4; ++mi) {
                    const f32x4 v = acc[mi][ni];
                    #pragma unroll
                    for (int q = 0; q < 4; ++q)
                        smem[(wm + mi * 16 + quad * 4 + q) * HP + nn] = f2bf(v[q] + bv);
                }
            }
            __syncthreads();

            // LIF scan, 2 adjacent columns per thread
            {
                const unsigned* smemU = (const unsigned*)smem;
                const int bb = tid >> 6;
                const int c2 = tid & 63;
                float v0 = 0.f, cv0 = 0.f, v1 = 0.f, cv1 = 0.f;
                #pragma unroll
                for (int t = 0; t < T_STEPS; ++t) {
                    const unsigned u = smemU[(t * 4 + bb) * (HP / 2) + c2];
                    const float h0 = bf2f((unsigned short)(u & 0xFFFFu));
                    const float h1 = bf2f((unsigned short)(u >> 16));
                    v0 = 0.5f * (v0 + h0);
                    const float s0 = (v0 >= 1.0f) ? 1.0f : 0.0f;
                    cv0 += s0; v0 *= (1.0f - s0);
                    v1 = 0.5f * (v1 + h1);
                    const float s1 = (v1 >= 1.0f) ? 1.0f : 0.0f;
                    cv1 += s1; v1 *= (1.0f - s1);
                }
                ushort2 o;
                o.x = f2bf(cv0); o.y = f2bf(cv1);
                *(ushort2*)&cnt[(size_t)(b0 + bb) * D_SZ + n0 + 2 * c2] = o;
            }
            __syncthreads();   // protect smem before next tile's STG
        }
#undef STG
#undef CMP
    }
    grid_sync(bar + 2, bar + 3);

    // ---- phase 3: gemm2 split-K (bid < 256; R3-proven body) ----
    if (bid < 256) {
        unsigned short* As = smem;          // 8 KiB
        unsigned short* Bs = smem + 4096;   // 8 KiB

        const int wave = tid >> 6;
        const int lane = tid & 63;
        const int lm   = lane & 15;
        const int quad = lane >> 4;
        const int wm   = (wave >> 1) * 64;
        const int wn   = (wave & 1) * 64;
        const int n0   = (bid & 7) * 128;
        const int m0   = ((bid >> 3) & 3) * 128;
        const int kz   = bid >> 5;

        f32x4 acc[4][4];
        #pragma unroll
        for (int i = 0; i < 4; ++i)
            #pragma unroll
            for (int j = 0; j < 4; ++j)
                acc[i][j] = (f32x4){0.f, 0.f, 0.f, 0.f};

        int srow[2], sgq[2];
        unsigned ldsoff[2];
        #pragma unroll
        for (int p = 0; p < 2; ++p) {
            const int s = p * 256 + tid;
            srow[p] = s >> 2;
            sgq[p]  = (s & 3) ^ ((srow[p] >> 1) & 3);
            ldsoff[p] = (unsigned)(p * 256 + wave * 64) * 16u;
        }
        const int fq = quad ^ ((lm >> 1) & 3);

        const int kbeg = kz * (D_SZ / KZ);
        for (int k0 = kbeg; k0 < kbeg + D_SZ / KZ; k0 += 32) {
            #pragma unroll
            for (int p = 0; p < 2; ++p) {
                async_copy16(cnt + (size_t)(m0 + srow[p]) * D_SZ + k0 + sgq[p] * 8,
                             (char*)As + ldsoff[p]);
                int brow = n0 + srow[p];
                if (brow > C_SZ - 1) brow = C_SZ - 1;
                async_copy16(W2_bf + (size_t)brow * D_SZ + k0 + sgq[p] * 8,
                             (char*)Bs + ldsoff[p]);
            }
            __syncthreads();

            bf16x8 af[4], bfr[4];
            #pragma unroll
            for (int i = 0; i < 4; ++i) {
                af[i]  = ((const bf16x8*)As)[(wm + i * 16 + lm) * 4 + fq];
                bfr[i] = ((const bf16x8*)Bs)[(wn + i * 16 + lm) * 4 + fq];
            }
            #pragma unroll
            for (int mi = 0; mi < 4; ++mi)
                #pragma unroll
                for (int ni = 0; ni < 4; ++ni)
                    acc[mi][ni] = __builtin_amdgcn_mfma_f32_16x16x32_bf16(
                        af[mi], bfr[ni], acc[mi][ni], 0, 0, 0);
            __syncthreads();
        }

        #pragma unroll
        for (int ni = 0; ni < 4; ++ni) {
            const int nn = n0 + wn + ni * 16 + lm;
            if (nn >= C_SZ) continue;
            #pragma unroll
            for (int mi = 0; mi < 4; ++mi) {
                const f32x4 v = acc[mi][ni];
                #pragma unroll
                for (int q = 0; q < 4; ++q) {
                    const int mm = m0 + wm + mi * 16 + quad * 4 + q;
                    partial[((size_t)kz * B_SZ + mm) * C_SZ + nn] = v[q];
                }
            }
        }
    }
    grid_sync(bar + 4, bar + 5);

    // ---- phase 4: reduce + bias + 1/T + log_softmax (1 block per batch row) --
    {
        float* red_max = (float*)smem;       // overlay (4 floats)
        float* red_sum = (float*)smem + 4;   // overlay (4 floats)
        const int b = bid;                   // NBLK == B_SZ == 512

        float vals[4];
        float m = -1e30f;
        #pragma unroll
        for (int k = 0; k < 4; ++k) {
            const int c = tid + k * 256;
            if (c < C_SZ) {
                float s = 0.f;
                #pragma unroll
                for (int z = 0; z < KZ; ++z)
                    s += partial[((size_t)z * B_SZ + b) * C_SZ + c];
                vals[k] = s * (1.0f / (float)T_STEPS) + b2[c];
            } else {
                vals[k] = -1e30f;
            }
            m = fmaxf(m, vals[k]);
        }
        #pragma unroll
        for (int off = 32; off > 0; off >>= 1)
            m = fmaxf(m, __shfl_down(m, off, 64));
        const int wave = tid >> 6;
        const int lane = tid & 63;
        if (lane == 0) red_max[wave] = m;
        __syncthreads();
        m = fmaxf(fmaxf(red_max[0], red_max[1]), fmaxf(red_max[2], red_max[3]));

        float s = 0.f;
        #pragma unroll
        for (int k = 0; k < 4; ++k) {
            const int c = tid + k * 256;
            if (c < C_SZ) s += __expf(vals[k] - m);
        }
        #pragma unroll
        for (int off = 32; off > 0; off >>= 1)
            s += __shfl_down(s, off, 64);
        if (lane == 0) red_sum[wave] = s;
        __syncthreads();
        s = red_sum[0] + red_sum[1] + red_sum[2] + red_sum[3];

        const float lse = m + logf(s);
        #pragma unroll
        for (int k = 0; k < 4; ++k) {
            const int c = tid + k * 256;
            if (c < C_SZ) out[(size_t)b * C_SZ + c] = vals[k] - lse;
        }
    }
}

extern "C" void kernel_launch(void* const* d_in, const int* in_sizes, int n_in,
                              void* d_out, int out_size, void* d_ws, size_t ws_size,
                              hipStream_t stream)
{
    const float* x  = (const float*)d_in[0];  // [T,B,D]
    const float* W1 = (const float*)d_in[1];  // [D,D]
    const float* b1 = (const float*)d_in[2];  // [D]
    const float* W2 = (const float*)d_in[3];  // [C,D]
    const float* b2 = (const float*)d_in[4];  // [C]
    float* out = (float*)d_out;               // [B,C]

    char* ws = (char*)d_ws;
    // X_bf [0, 33,554,432); partial overlaps X_bf (X_bf dead before phase 3
    // writes partial — enforced by the grid barriers / kernel order).
    unsigned short* X_bf    = (unsigned short*)(ws);
    float*          partial = (float*)(ws);                      // 16,384,000 B
    unsigned short* W1_bf   = (unsigned short*)(ws + 33554432);  //  2,097,152 B
    unsigned short* W2_bf   = (unsigned short*)(ws + 35651584);  //  2,048,000 B
    unsigned short* cnt_bf  = (unsigned short*)(ws + 37699584);  //  1,048,576 B
    unsigned*       bar     = (unsigned*)(ws + 38748160);        //         64 B
    // peak = 38,748,224 B

    if (ws_size >= 38748224u) {
        // zero barrier state every replay (graph-legal memset node; barriers
        // also self-reset, so this is belt-and-suspenders for dirty ws)
        (void)hipMemsetAsync(bar, 0, 64, stream);
        fused_all_k<<<NBLK, 256, 0, stream>>>(
            x, W1, b1, W2, b2, X_bf, W1_bf, W2_bf, cnt_bf, partial, out, bar);
    } else {
        // R3-proven 4-kernel chain (ws_size >= 38,748,160 established in R3)
        cast_all_k<<<NCTOT / 256, 256, 0, stream>>>(x, X_bf, W1, W1_bf, W2, W2_bf);
        gemm1_scan_bf_k<<<(B_SZ / 4) * (D_SZ / 128), 256, 0, stream>>>(
            X_bf, W1_bf, b1, cnt_bf);
        dim3 g2((C_SZ + 127) / 128, B_SZ / 128, KZ);
        gemm2_splitk_k<<<g2, 256, 0, stream>>>(cnt_bf, W2_bf, partial);
        reduce_lsm_k<<<B_SZ, 256, 0, stream>>>(partial, b2, out);
    }
}

// Round 6
// 152.155 us; speedup vs baseline: 2.1476x; 2.1476x over previous
//
#include <hip/hip_runtime.h>
#include <math.h>

#define T_STEPS 32
#define B_SZ    512
#define D_SZ    1024
#define C_SZ    1000
#define KZ      8           // GEMM2 split-K factor
#define HP      132         // LDS h-tile pitch for the 128^2 fallback kernel

typedef __bf16 bf16x8 __attribute__((ext_vector_type(8)));
typedef float  f32x4  __attribute__((ext_vector_type(4)));

__device__ __forceinline__ unsigned short f2bf(float f) {
    unsigned u = __float_as_uint(f);
    unsigned r = u + 0x7FFFu + ((u >> 16) & 1u);   // RNE
    return (unsigned short)(r >> 16);
}
__device__ __forceinline__ float bf2f(unsigned short b) {
    return __uint_as_float(((unsigned)b) << 16);
}

__device__ __forceinline__ void async_copy16(const void* g, void* l) {
    __builtin_amdgcn_global_load_lds(
        (const __attribute__((address_space(1))) unsigned int*)g,
        (__attribute__((address_space(3))) unsigned int*)l,
        16, 0, 0);
}

// pack 8 fp32 -> 8 bf16 (RNE via compiler cvt) — fallback kernel only
__device__ __forceinline__ bf16x8 cvt8(const float4 u, const float4 v) {
    bf16x8 r;
    r[0] = (__bf16)u.x; r[1] = (__bf16)u.y; r[2] = (__bf16)u.z; r[3] = (__bf16)u.w;
    r[4] = (__bf16)v.x; r[5] = (__bf16)v.y; r[6] = (__bf16)v.z; r[7] = (__bf16)v.w;
    return r;
}

// ---------------- cast sizes --------------------------------------------------
#define NX4   4194304   // X:  16M floats / 4
#define NW14  262144    // W1:  1M floats / 4
#define NW24  256000    // W2: 1.024M floats / 4
#define NWTOT (NW14 + NW24)          // 518,144 = 2024 * 256
#define NCTOT (NX4 + NW14 + NW24)    // 4,712,448 = 18,408 * 256

__global__ __launch_bounds__(256) void cast_all_k(
    const float* __restrict__ X,  unsigned short* __restrict__ X_bf,
    const float* __restrict__ W1, unsigned short* __restrict__ W1_bf,
    const float* __restrict__ W2, unsigned short* __restrict__ W2_bf)
{
    const int idx = blockIdx.x * 256 + threadIdx.x;
    const float4* s; ushort4* d; int j;
    if (idx < NX4)              { s = (const float4*)X;  d = (ushort4*)X_bf;  j = idx; }
    else if (idx < NX4 + NW14)  { s = (const float4*)W1; d = (ushort4*)W1_bf; j = idx - NX4; }
    else                        { s = (const float4*)W2; d = (ushort4*)W2_bf; j = idx - NX4 - NW14; }
    const float4 v = s[j];
    ushort4 o;
    o.x = f2bf(v.x); o.y = f2bf(v.y); o.z = f2bf(v.z); o.w = f2bf(v.w);
    d[j] = o;
}

__global__ __launch_bounds__(256) void cast_w_k(
    const float* __restrict__ W1, unsigned short* __restrict__ W1_bf,
    const float* __restrict__ W2, unsigned short* __restrict__ W2_bf)
{
    const int idx = blockIdx.x * 256 + threadIdx.x;
    const float4* s; ushort4* d; int j;
    if (idx < NW14) { s = (const float4*)W1; d = (ushort4*)W1_bf; j = idx; }
    else            { s = (const float4*)W2; d = (ushort4*)W2_bf; j = idx - NW14; }
    const float4 v = s[j];
    ushort4 o;
    o.x = f2bf(v.x); o.y = f2bf(v.y); o.z = f2bf(v.z); o.w = f2bf(v.w);
    d[j] = o;
}

// ---------------- MAIN gemm1: 256x256 tile, 8 waves, 4-phase K-step -----------
// Tile 256(M=32t x 8b) x 256(N); BK=64; 8 waves (2M x 4N), per-wave out 128x64.
// LDS 128 KiB: A dbuf 2x32K + B dbuf 2x32K, per-row 8x16B chunk-XOR swizzle
// (proven 0-conflict in all prior rounds). Per K-step: 4 phases, each
// {ds_read quadrant | stage-issue -> s_barrier -> 16 MFMA (setprio) -> s_barrier}.
// DMA for tile t+1 issued in phases 0-1 (A) / 1 (B) => 2-3 MFMA clusters of
// latency cover before the end-of-step __syncthreads drain.
__global__ __launch_bounds__(512, 2) void gemm1_scan256_k(
    const unsigned short* __restrict__ Xb, const unsigned short* __restrict__ Bm,
    const float* __restrict__ bias, unsigned short* __restrict__ cnt)
{
    __shared__ __align__(16) unsigned short smem[65536];   // 128 KiB

    const int tid  = threadIdx.x;
    const int wave = tid >> 6;
    const int lane = tid & 63;
    const int lm   = lane & 15;
    const int quad = lane >> 4;
    const int wm   = (wave >> 2) * 128;      // 2 M-waves
    const int wn   = (wave & 3) * 64;        // 4 N-waves

    // XCD-chunked bijective swizzle (256 blocks, 256%8==0): XCD c (= bid&7)
    // owns wgid c*32..c*32+31 -> 8 contiguous yb x all 4 xb => 4 MB A-slab/XCD.
    const int wgid = (blockIdx.x & 7) * 32 + (blockIdx.x >> 3);
    const int yb = wgid >> 2;                // 0..63
    const int xb = wgid & 3;                 // 0..3
    const int b0 = yb * 8;                   // batch rows b0..b0+7
    const int n0 = xb * 256;                 // output cols n0..n0+255

    f32x4 acc[8][4];
    #pragma unroll
    for (int i = 0; i < 8; ++i)
        #pragma unroll
        for (int j = 0; j < 4; ++j)
            acc[i][j] = (f32x4){0.f, 0.f, 0.f, 0.f};

    // staging: slot s = p*512+tid; rho = s>>3 (0..255); phys chunk q = s&7;
    // data chunk gq = q ^ (rho&7). M-row rho -> global X row (rho>>3)*512+b0+(rho&7).
    size_t aoff[4], boff[4];
    unsigned ldsoffp[4];
    #pragma unroll
    for (int p = 0; p < 4; ++p) {
        const int s   = p * 512 + tid;
        const int rho = s >> 3;
        const int gq  = (s & 7) ^ (rho & 7);
        aoff[p] = (size_t)((rho >> 3) * 512 + b0 + (rho & 7)) * D_SZ + gq * 8;
        boff[p] = (size_t)(n0 + rho) * D_SZ + gq * 8;
        ldsoffp[p] = (unsigned)(p * 512 + wave * 64) * 16u;  // wave-uniform base
    }
    const int fq0 = quad ^ (lm & 7);

#define STG_A(cb_, k0_) do {                                                     \
        char* ab_ = (char*)smem + (cb_) * 32768;                                 \
        _Pragma("unroll")                                                        \
        for (int p = 0; p < 4; ++p)                                              \
            async_copy16(Xb + aoff[p] + (k0_), ab_ + ldsoffp[p]);                \
    } while (0)

#define STG_B(cb_, k0_) do {                                                     \
        char* bb_ = (char*)smem + 65536 + (cb_) * 32768;                         \
        _Pragma("unroll")                                                        \
        for (int p = 0; p < 4; ++p)                                              \
            async_copy16(Bm + boff[p] + (k0_), bb_ + ldsoffp[p]);                \
    } while (0)

#define READ_A(mi0_) do {                                                        \
        _Pragma("unroll")                                                        \
        for (int m2 = 0; m2 < 2; ++m2) {                                         \
            const int rw_ = wm + ((mi0_) + m2) * 16 + lm;                        \
            af[m2][0] = Ar[rw_ * 8 + fq0];                                       \
            af[m2][1] = Ar[rw_ * 8 + (fq0 ^ 4)];                                 \
        }                                                                        \
    } while (0)

#define MFMA2(mi0_) do {                                                         \
        __builtin_amdgcn_s_setprio(1);                                           \
        _Pragma("unroll")                                                        \
        for (int kk = 0; kk < 2; ++kk)                                           \
            _Pragma("unroll")                                                    \
            for (int m2 = 0; m2 < 2; ++m2)                                       \
                _Pragma("unroll")                                                \
                for (int ni = 0; ni < 4; ++ni)                                   \
                    acc[(mi0_) + m2][ni] = __builtin_amdgcn_mfma_f32_16x16x32_bf16( \
                        af[m2][kk], bfr[ni][kk], acc[(mi0_) + m2][ni], 0, 0, 0); \
        __builtin_amdgcn_s_setprio(0);                                           \
    } while (0)

    // prologue: tile 0 -> buf 0
    STG_A(0, 0);
    STG_B(0, 0);
    __syncthreads();

    #pragma unroll 2
    for (int t = 0; t < 16; ++t) {
        const int c  = t & 1;
        const bf16x8* Ar = (const bf16x8*)((const char*)smem + c * 32768);
        const bf16x8* Br = (const bf16x8*)((const char*)smem + 65536 + c * 32768);
        const int kn = (t + 1) * 64;
        bf16x8 bfr[4][2], af[2][2];

        // phase 0: all B-frags + A mi{0,1}; issue A-DMA(t+1)
        #pragma unroll
        for (int ni = 0; ni < 4; ++ni) {
            const int rw = (wn + ni * 16 + lm) * 8;
            bfr[ni][0] = Br[rw + fq0];
            bfr[ni][1] = Br[rw + (fq0 ^ 4)];
        }
        READ_A(0);
        if (t < 15) STG_A(c ^ 1, kn);
        __builtin_amdgcn_s_barrier();
        MFMA2(0);
        __builtin_amdgcn_s_barrier();

        // phase 1: A mi{2,3}; issue B-DMA(t+1)
        READ_A(2);
        if (t < 15) STG_B(c ^ 1, kn);
        __builtin_amdgcn_s_barrier();
        MFMA2(2);
        __builtin_amdgcn_s_barrier();

        // phase 2: A mi{4,5}
        READ_A(4);
        __builtin_amdgcn_s_barrier();
        MFMA2(4);
        __builtin_amdgcn_s_barrier();

        // phase 3: A mi{6,7}
        READ_A(6);
        __builtin_amdgcn_s_barrier();
        MFMA2(6);
        __syncthreads();   // drains vmcnt (DMA t+1, ~2-3 phases of cover) + lgkm
    }

#undef STG_A
#undef STG_B
#undef READ_A
#undef MFMA2

    // h-tile (+bias) -> LDS, pitch 256 with quad-XOR column swizzle:
    // store at col ^ (((row>>2)&3)<<4)  => write banks = (col/2)^(quad<<3):
    // 4 disjoint 8-blocks x 16 lm = 32 banks, 2-way (free). Bijective per row.
    #pragma unroll
    for (int ni = 0; ni < 4; ++ni) {
        const int col = wn + ni * 16 + lm;
        const float bv = bias[n0 + col];
        #pragma unroll
        for (int mi = 0; mi < 8; ++mi) {
            const f32x4 v = acc[mi][ni];
            #pragma unroll
            for (int q = 0; q < 4; ++q) {
                const int row = wm + mi * 16 + quad * 4 + q;
                smem[row * 256 + (col ^ (((row >> 2) & 3) << 4))] = f2bf(v[q] + bv);
            }
        }
    }
    __syncthreads();

    // LIF scan: 512 threads; thread -> uint col uc (2 adjacent d), 2 batch rows.
    {
        const unsigned* smemU = (const unsigned*)smem;
        const int uc = tid & 127;         // uint col 0..127 (d pair)
        const int h4 = tid >> 7;          // 0..3
        #pragma unroll
        for (int g = 0; g < 2; ++g) {
            const int bb = h4 + g * 4;    // batch row within tile 0..7
            float v0 = 0.f, cv0 = 0.f, v1 = 0.f, cv1 = 0.f;
            #pragma unroll
            for (int t2 = 0; t2 < T_STEPS; ++t2) {
                const int rho = t2 * 8 + bb;
                const unsigned u =
                    smemU[rho * 128 + (uc ^ (((rho >> 2) & 3) << 3))];
                const float h0 = bf2f((unsigned short)(u & 0xFFFFu));
                const float h1 = bf2f((unsigned short)(u >> 16));
                v0 = 0.5f * (v0 + h0);
                const float s0 = (v0 >= 1.0f) ? 1.0f : 0.0f;
                cv0 += s0; v0 *= (1.0f - s0);
                v1 = 0.5f * (v1 + h1);
                const float s1 = (v1 >= 1.0f) ? 1.0f : 0.0f;
                cv1 += s1; v1 *= (1.0f - s1);
            }
            ushort2 o;
            o.x = f2bf(cv0); o.y = f2bf(cv1);
            *(ushort2*)&cnt[(size_t)(b0 + bb) * D_SZ + n0 + 2 * uc] = o;
        }
    }
}

// ---------------- FALLBACK gemm1 (R1-proven): fp32 A reg-staged, 128^2 --------
__global__ __launch_bounds__(256) void gemm1_scan_f32_k(
    const float* __restrict__ X, const unsigned short* __restrict__ Bm,
    const float* __restrict__ bias, unsigned short* __restrict__ cnt)
{
    __shared__ __align__(16) unsigned short smem[32768];   // 64 KiB

    const int tid  = threadIdx.x;
    const int wave = tid >> 6;
    const int lane = tid & 63;
    const int lm   = lane & 15;
    const int quad = lane >> 4;
    const int wm   = (wave >> 1) * 64;
    const int wn   = (wave & 1) * 64;

    const int f  = blockIdx.x;
    const int rr = f >> 9;
    const int cc = f & 7;
    const int ss = (f >> 3) & 63;
    const int xb = ss & 7;
    const int yb = rr * 64 + (ss >> 3) * 8 + cc;
    const int b0 = yb * 4;
    const int n0 = xb * 128;

    f32x4 acc[4][4];
    #pragma unroll
    for (int i = 0; i < 4; ++i)
        #pragma unroll
        for (int j = 0; j < 4; ++j)
            acc[i][j] = (f32x4){0.f, 0.f, 0.f, 0.f};

    int srow[4], sgq[4];
    size_t arowoff[4];
    unsigned ldsoffB[4];
    #pragma unroll
    for (int p = 0; p < 4; ++p) {
        const int s = p * 256 + tid;
        const int rho = s >> 3;
        srow[p] = rho;
        sgq[p]  = (s & 7) ^ (rho & 7);
        arowoff[p] = (size_t)((rho >> 2) * 512 + b0 + (rho & 3)) * D_SZ;
        ldsoffB[p] = (unsigned)(p * 256 + wave * 64) * 16u;
    }
    const int fq0 = quad ^ (lm & 7);

    float4 au[4], av[4];

#define LOAD_A(k0_) do {                                                        \
        _Pragma("unroll")                                                       \
        for (int p = 0; p < 4; ++p) {                                           \
            const float* srcp = X + arowoff[p] + (k0_) + sgq[p] * 8;            \
            au[p] = *(const float4*)(srcp);                                     \
            av[p] = *(const float4*)(srcp + 4);                                 \
        }                                                                       \
    } while (0)

#define STAGE_B(buf_, k0_) do {                                                 \
        char* bdst = (char*)(smem + 16384 + (buf_) * 8192);                     \
        _Pragma("unroll")                                                       \
        for (int p = 0; p < 4; ++p)                                             \
            async_copy16(Bm + (size_t)(n0 + srow[p]) * D_SZ + (k0_) + sgq[p] * 8,\
                         bdst + ldsoffB[p]);                                    \
    } while (0)

#define WRITE_A(buf_) do {                                                      \
        bf16x8* adst = (bf16x8*)(smem + (buf_) * 8192);                         \
        _Pragma("unroll")                                                       \
        for (int p = 0; p < 4; ++p)                                             \
            adst[p * 256 + tid] = cvt8(au[p], av[p]);                           \
    } while (0)

#define COMPUTE(buf_) do {                                                      \
        const bf16x8* Ar = (const bf16x8*)(smem + (buf_) * 8192);               \
        const bf16x8* Br = (const bf16x8*)(smem + 16384 + (buf_) * 8192);       \
        __builtin_amdgcn_s_setprio(1);                                          \
        _Pragma("unroll")                                                       \
        for (int kk = 0; kk < 2; ++kk) {                                        \
            const int fqk = fq0 ^ (kk * 4);                                     \
            bf16x8 af[4], bfr[4];                                               \
            _Pragma("unroll")                                                   \
            for (int i2 = 0; i2 < 4; ++i2) {                                    \
                af[i2]  = Ar[(wm + i2 * 16 + lm) * 8 + fqk];                    \
                bfr[i2] = Br[(wn + i2 * 16 + lm) * 8 + fqk];                    \
            }                                                                   \
            _Pragma("unroll")                                                   \
            for (int mi = 0; mi < 4; ++mi)                                      \
                _Pragma("unroll")                                               \
                for (int ni = 0; ni < 4; ++ni)                                  \
                    acc[mi][ni] = __builtin_amdgcn_mfma_f32_16x16x32_bf16(      \
                        af[mi], bfr[ni], acc[mi][ni], 0, 0, 0);                 \
        }                                                                       \
        __builtin_amdgcn_s_setprio(0);                                          \
    } while (0)

    LOAD_A(0);
    STAGE_B(0, 0);
    WRITE_A(0);
    __syncthreads();
    LOAD_A(64);
    STAGE_B(1, 64);

    for (int i = 0; i < 14; i += 2) {
        COMPUTE(0);
        WRITE_A(1);
        __syncthreads();
        LOAD_A((i + 2) * 64);
        STAGE_B(0, (i + 2) * 64);

        COMPUTE(1);
        WRITE_A(0);
        __syncthreads();
        LOAD_A((i + 3) * 64);
        STAGE_B(1, (i + 3) * 64);
    }
    COMPUTE(0);
    WRITE_A(1);
    __syncthreads();
    COMPUTE(1);
    __syncthreads();

#undef LOAD_A
#undef STAGE_B
#undef WRITE_A
#undef COMPUTE

    #pragma unroll
    for (int ni = 0; ni < 4; ++ni) {
        const int nn = wn + ni * 16 + lm;
        const float bv = bias[n0 + nn];
        #pragma unroll
        for (int mi = 0; mi < 4; ++mi) {
            const f32x4 v = acc[mi][ni];
            #pragma unroll
            for (int q = 0; q < 4; ++q)
                smem[(wm + mi * 16 + quad * 4 + q) * HP + nn] = f2bf(v[q] + bv);
        }
    }
    __syncthreads();

    {
        const unsigned* smemU = (const unsigned*)smem;
        const int bb = tid >> 6;
        const int c2 = tid & 63;
        float v0 = 0.f, cv0 = 0.f, v1 = 0.f, cv1 = 0.f;
        #pragma unroll
        for (int t = 0; t < T_STEPS; ++t) {
            const unsigned u = smemU[(t * 4 + bb) * (HP / 2) + c2];
            const float h0 = bf2f((unsigned short)(u & 0xFFFFu));
            const float h1 = bf2f((unsigned short)(u >> 16));
            v0 = 0.5f * (v0 + h0);
            const float s0 = (v0 >= 1.0f) ? 1.0f : 0.0f;
            cv0 += s0; v0 *= (1.0f - s0);
            v1 = 0.5f * (v1 + h1);
            const float s1 = (v1 >= 1.0f) ? 1.0f : 0.0f;
            cv1 += s1; v1 *= (1.0f - s1);
        }
        ushort2 o;
        o.x = f2bf(cv0); o.y = f2bf(cv1);
        *(ushort2*)&cnt[(size_t)(b0 + bb) * D_SZ + n0 + 2 * c2] = o;
    }
}

// ---------------- GEMM2 split-K: partial[z][m][n] = cnt @ W2^T (K-slice) ------
__global__ __launch_bounds__(256) void gemm2_splitk_k(
    const unsigned short* __restrict__ A, const unsigned short* __restrict__ Bm,
    float* __restrict__ partial)
{
    __shared__ __align__(16) unsigned short As[128 * 32];
    __shared__ __align__(16) unsigned short Bs[128 * 32];

    const int tid  = threadIdx.x;
    const int wave = tid >> 6;
    const int lane = tid & 63;
    const int lm   = lane & 15;
    const int quad = lane >> 4;
    const int wm   = (wave >> 1) * 64;
    const int wn   = (wave & 1) * 64;
    const int n0   = blockIdx.x * 128;
    const int m0   = blockIdx.y * 128;
    const int kz   = blockIdx.z;

    f32x4 acc[4][4];
    #pragma unroll
    for (int i = 0; i < 4; ++i)
        #pragma unroll
        for (int j = 0; j < 4; ++j)
            acc[i][j] = (f32x4){0.f, 0.f, 0.f, 0.f};

    int srow[2], sgq[2];
    unsigned ldsoff[2];
    #pragma unroll
    for (int p = 0; p < 2; ++p) {
        const int s = p * 256 + tid;
        srow[p] = s >> 2;
        sgq[p]  = (s & 3) ^ ((srow[p] >> 1) & 3);
        ldsoff[p] = (unsigned)(p * 256 + wave * 64) * 16u;
    }
    const int fq = quad ^ ((lm >> 1) & 3);

    const int kbeg = kz * (D_SZ / KZ);
    for (int k0 = kbeg; k0 < kbeg + D_SZ / KZ; k0 += 32) {
        #pragma unroll
        for (int p = 0; p < 2; ++p) {
            async_copy16(A + (size_t)(m0 + srow[p]) * D_SZ + k0 + sgq[p] * 8,
                         (char*)As + ldsoff[p]);
            int brow = n0 + srow[p];
            if (brow > C_SZ - 1) brow = C_SZ - 1;
            async_copy16(Bm + (size_t)brow * D_SZ + k0 + sgq[p] * 8,
                         (char*)Bs + ldsoff[p]);
        }
        __syncthreads();

        bf16x8 af[4], bfr[4];
        #pragma unroll
        for (int i = 0; i < 4; ++i) {
            af[i]  = ((const bf16x8*)As)[(wm + i * 16 + lm) * 4 + fq];
            bfr[i] = ((const bf16x8*)Bs)[(wn + i * 16 + lm) * 4 + fq];
        }
        #pragma unroll
        for (int mi = 0; mi < 4; ++mi)
            #pragma unroll
            for (int ni = 0; ni < 4; ++ni)
                acc[mi][ni] = __builtin_amdgcn_mfma_f32_16x16x32_bf16(
                    af[mi], bfr[ni], acc[mi][ni], 0, 0, 0);
        __syncthreads();
    }

    #pragma unroll
    for (int ni = 0; ni < 4; ++ni) {
        const int nn = n0 + wn + ni * 16 + lm;
        if (nn >= C_SZ) continue;
        #pragma unroll
        for (int mi = 0; mi < 4; ++mi) {
            const f32x4 v = acc[mi][ni];
            #pragma unroll
            for (int q = 0; q < 4; ++q) {
                const int mm = m0 + wm + mi * 16 + quad * 4 + q;
                partial[((size_t)kz * B_SZ + mm) * C_SZ + nn] = v[q];
            }
        }
    }
}

// ---------------- reduce partials + bias + log_softmax ----------------
__global__ __launch_bounds__(256) void reduce_lsm_k(
    const float* __restrict__ partial, const float* __restrict__ b2,
    float* __restrict__ out)
{
    __shared__ float red_max[4];
    __shared__ float red_sum[4];

    const int b   = blockIdx.x;
    const int tid = threadIdx.x;

    float vals[4];
    float m = -1e30f;
    #pragma unroll
    for (int k = 0; k < 4; ++k) {
        const int c = tid + k * 256;
        if (c < C_SZ) {
            float s = 0.f;
            #pragma unroll
            for (int z = 0; z < KZ; ++z)
                s += partial[((size_t)z * B_SZ + b) * C_SZ + c];
            vals[k] = s * (1.0f / (float)T_STEPS) + b2[c];
        } else {
            vals[k] = -1e30f;
        }
        m = fmaxf(m, vals[k]);
    }
    #pragma unroll
    for (int off = 32; off > 0; off >>= 1)
        m = fmaxf(m, __shfl_down(m, off, 64));
    const int wave = tid >> 6;
    const int lane = tid & 63;
    if (lane == 0) red_max[wave] = m;
    __syncthreads();
    m = fmaxf(fmaxf(red_max[0], red_max[1]), fmaxf(red_max[2], red_max[3]));

    float s = 0.f;
    #pragma unroll
    for (int k = 0; k < 4; ++k) {
        const int c = tid + k * 256;
        if (c < C_SZ) s += __expf(vals[k] - m);
    }
    #pragma unroll
    for (int off = 32; off > 0; off >>= 1)
        s += __shfl_down(s, off, 64);
    if (lane == 0) red_sum[wave] = s;
    __syncthreads();
    s = red_sum[0] + red_sum[1] + red_sum[2] + red_sum[3];

    const float lse = m + logf(s);
    #pragma unroll
    for (int k = 0; k < 4; ++k) {
        const int c = tid + k * 256;
        if (c < C_SZ) out[(size_t)b * C_SZ + c] = vals[k] - lse;
    }
}

extern "C" void kernel_launch(void* const* d_in, const int* in_sizes, int n_in,
                              void* d_out, int out_size, void* d_ws, size_t ws_size,
                              hipStream_t stream)
{
    const float* x  = (const float*)d_in[0];  // [T,B,D]
    const float* W1 = (const float*)d_in[1];  // [D,D]
    const float* b1 = (const float*)d_in[2];  // [D]
    const float* W2 = (const float*)d_in[3];  // [C,D]
    const float* b2 = (const float*)d_in[4];  // [C]
    float* out = (float*)d_out;               // [B,C]

    char* ws = (char*)d_ws;

    if (ws_size >= 38748160u) {
        // ---- main path (R3-proven layout): X_bf overlaps partial ----
        unsigned short* X_bf    = (unsigned short*)(ws);
        float*          partial = (float*)(ws);                      // 16,384,000 B
        unsigned short* W1_bf   = (unsigned short*)(ws + 33554432);  //  2,097,152 B
        unsigned short* W2_bf   = (unsigned short*)(ws + 35651584);  //  2,048,000 B
        unsigned short* cnt_bf  = (unsigned short*)(ws + 37699584);  //  1,048,576 B
        // peak = 38,748,160 B (proven in R3)

        cast_all_k<<<NCTOT / 256, 256, 0, stream>>>(x, X_bf, W1, W1_bf, W2, W2_bf);
        gemm1_scan256_k<<<256, 512, 0, stream>>>(X_bf, W1_bf, b1, cnt_bf);
        {
            dim3 grid((C_SZ + 127) / 128, B_SZ / 128, KZ);
            gemm2_splitk_k<<<grid, 256, 0, stream>>>(cnt_bf, W2_bf, partial);
        }
        reduce_lsm_k<<<B_SZ, 256, 0, stream>>>(partial, b2, out);
    } else {
        // ---- fallback (R1-proven layout, 21,577,728 B) ----
        unsigned short* W1_bf   = (unsigned short*)(ws);
        unsigned short* W2_bf   = (unsigned short*)(ws + 2097152);
        unsigned short* cnt_bf  = (unsigned short*)(ws + 4145152);
        float*          partial = (float*)(ws + 5193728);

        cast_w_k<<<NWTOT / 256, 256, 0, stream>>>(W1, W1_bf, W2, W2_bf);
        gemm1_scan_f32_k<<<(B_SZ / 4) * (D_SZ / 128), 256, 0, stream>>>(
            x, W1_bf, b1, cnt_bf);
        {
            dim3 grid((C_SZ + 127) / 128, B_SZ / 128, KZ);
            gemm2_splitk_k<<<grid, 256, 0, stream>>>(cnt_bf, W2_bf, partial);
        }
        reduce_lsm_k<<<B_SZ, 256, 0, stream>>>(partial, b2, out);
    }
}